// Round 2
// baseline (693.458 us; speedup 1.0000x reference)
//
#include <hip/hip_runtime.h>
#include <hip/hip_bf16.h>

// GCN 3-layer forward on gfx950, dtype-robust version.
// flags[0] = 1 if float inputs/outputs are f32, 0 if bf16.
// flags[1] = 1 if edge_index is int64, 0 if int32.
// Detected on-device each launch (graph-capture safe, identical work per call).
//
// Pipeline: detect -> memset cnt -> count_edges -> scan(off,cur,dinv)
//           -> fill_csr -> [gemm_scale -> aggregate] x3
// g = dinv*(X@W) in GEMM epilogue; aggregation = CSR gather-sum with
// self-loop as accumulator init; bias(+relu) in aggregate epilogue.
// Intermediates f32 in d_ws; d_out written in detected dtype.

__device__ __forceinline__ float tof(float v) { return v; }
__device__ __forceinline__ float tof(__hip_bfloat16 v) { return __bfloat162float(v); }

__global__ void detect_dtypes(const void* __restrict__ x,
                              const void* __restrict__ ei,
                              int* __restrict__ flags) {
    if (threadIdx.x == 0) {
        // If x is f32, even 16-bit halves are low mantissa bits -> bf16-exp
        // field ~uniform. If bf16, exponents of N(0,1) samples sit in ~[117,130].
        const unsigned short* p = (const unsigned short*)x;
        int bad = 0;
        for (int j = 0; j < 256; ++j) {
            int e = (p[2 * j] >> 7) & 0xFF;
            if (e < 100 || e > 140) ++bad;
        }
        flags[0] = (bad > 64) ? 1 : 0;
    }
    if (threadIdx.x == 1) {
        // int64 values < 50000 -> every odd int32 word is 0.
        const int* p = (const int*)ei;
        int nz = 0;
        for (int j = 0; j < 256; ++j) nz += (p[2 * j + 1] != 0);
        flags[1] = (nz < 8) ? 1 : 0;
    }
}

__device__ __forceinline__ int edge_at(const void* ei, long long idx, bool i64) {
    return i64 ? (int)((const long long*)ei)[idx] : ((const int*)ei)[idx];
}

__global__ void count_edges(const void* __restrict__ ei, int* __restrict__ cnt,
                            const int* __restrict__ flags, int e) {
    int i = blockIdx.x * 256 + threadIdx.x;
    if (i < e) {
        const bool i64 = flags[1] != 0;
        atomicAdd(&cnt[edge_at(ei, (long long)e + i, i64)], 1);
    }
}

__global__ __launch_bounds__(1024) void scan_kernel(const int* __restrict__ cnt,
                                                    int* __restrict__ off,
                                                    int* __restrict__ cur,
                                                    float* __restrict__ dinv,
                                                    int n, int e_total) {
    __shared__ int part[1024];
    const int t = threadIdx.x;
    const int CH = (n + 1023) >> 10;
    const int lo = t * CH;
    const int hi = min(lo + CH, n);
    int s = 0;
    for (int i = lo; i < hi; ++i) s += cnt[i];
    part[t] = s;
    __syncthreads();
    for (int d = 1; d < 1024; d <<= 1) {
        int v = (t >= d) ? part[t - d] : 0;
        __syncthreads();
        part[t] += v;
        __syncthreads();
    }
    int base = (t == 0) ? 0 : part[t - 1];
    for (int i = lo; i < hi; ++i) {
        off[i] = base;
        cur[i] = base;
        int c = cnt[i];
        dinv[i] = rsqrtf((float)(c + 1));
        base += c;
    }
    if (t == 1023) off[n] = e_total;
}

__global__ void fill_csr(const void* __restrict__ ei, int* __restrict__ cur,
                         int* __restrict__ csr_src, const int* __restrict__ flags, int e) {
    int i = blockIdx.x * 256 + threadIdx.x;
    if (i < e) {
        const bool i64 = flags[1] != 0;
        int r = edge_at(ei, i, i64);
        int c = edge_at(ei, (long long)e + i, i64);
        int p = atomicAdd(&cur[c], 1);
        csr_src[p] = r;
    }
}

// G[i][c] = dinv[i] * sum_k X[i][k]*W[k][c]. 256 threads, 16 rows x COUT/blk.
// XFLAG: X dtype follows flags[0]; otherwise X is f32 (workspace buffer).
template <bool XFLAG, int COUT>
__global__ __launch_bounds__(256) void gemm_scale(const void* __restrict__ Xv,
                                                  const void* __restrict__ Wv,
                                                  const float* __restrict__ dinv,
                                                  float* __restrict__ G,
                                                  const int* __restrict__ flags, int n) {
    constexpr int ROWS = 16;
    constexpr int KC = 64;
    __shared__ float wlds[KC * COUT];
    __shared__ float xlds[ROWS * 128];
    const int t = threadIdx.x;
    const int row0 = blockIdx.x * ROWS;
    const bool f32 = flags[0] != 0;
    const bool xf32 = XFLAG ? f32 : true;

    if (xf32) {
        const float* X = (const float*)Xv;
        for (int i = t; i < ROWS * 128; i += 256) {
            int r = i >> 7;
            xlds[i] = (row0 + r < n) ? X[(size_t)(row0 + r) * 128 + (i & 127)] : 0.f;
        }
    } else {
        const __hip_bfloat16* X = (const __hip_bfloat16*)Xv;
        for (int i = t; i < ROWS * 128; i += 256) {
            int r = i >> 7;
            xlds[i] = (row0 + r < n) ? tof(X[(size_t)(row0 + r) * 128 + (i & 127)]) : 0.f;
        }
    }

    float acc[8];
#pragma unroll
    for (int j = 0; j < 8; ++j) acc[j] = 0.f;

    const int c4 = (COUT == 128) ? ((t & 31) * 4) : ((t & 15) * 4);
    const int r0 = (COUT == 128) ? ((t >> 5) * 2) : (t >> 4);

    for (int kc = 0; kc < 128; kc += KC) {
        __syncthreads();
        if (f32) {
            const float* W = (const float*)Wv;
            for (int i = t; i < KC * COUT; i += 256)
                wlds[i] = W[(size_t)kc * COUT + i];
        } else {
            const __hip_bfloat16* W = (const __hip_bfloat16*)Wv;
            for (int i = t; i < KC * COUT; i += 256)
                wlds[i] = tof(W[(size_t)kc * COUT + i]);
        }
        __syncthreads();
#pragma unroll
        for (int k = 0; k < KC; ++k) {
            const float4 w = *(const float4*)&wlds[k * COUT + c4];
            if (COUT == 128) {
                float x0 = xlds[r0 * 128 + kc + k];
                float x1 = xlds[(r0 + 1) * 128 + kc + k];
                acc[0] += x0 * w.x; acc[1] += x0 * w.y;
                acc[2] += x0 * w.z; acc[3] += x0 * w.w;
                acc[4] += x1 * w.x; acc[5] += x1 * w.y;
                acc[6] += x1 * w.z; acc[7] += x1 * w.w;
            } else {
                float x0 = xlds[r0 * 128 + kc + k];
                acc[0] += x0 * w.x; acc[1] += x0 * w.y;
                acc[2] += x0 * w.z; acc[3] += x0 * w.w;
            }
        }
    }

    const int nr = (COUT == 128) ? 2 : 1;
#pragma unroll
    for (int rr = 0; rr < nr; ++rr) {
        int row = row0 + r0 + rr;
        if (row < n) {
            float d = dinv[row];
            float4 o;
            o.x = d * acc[rr * 4 + 0];
            o.y = d * acc[rr * 4 + 1];
            o.z = d * acc[rr * 4 + 2];
            o.w = d * acc[rr * 4 + 3];
            *(float4*)&G[(size_t)row * COUT + c4] = o;
        }
    }
}

// One wave per destination node; lane handles CPL channels (CPL*64 == C).
// acc init = self-loop row G[node]; gather-sum csr rows; out = [relu](d*acc+b).
// WWS: also write f32 to Hf (workspace). WOUT: write d_out in detected dtype.
template <int CPL, bool RELU, bool WWS, bool WOUT>
__global__ __launch_bounds__(256) void aggregate(const float* __restrict__ G,
                                                 const int* __restrict__ off,
                                                 const int* __restrict__ csr_src,
                                                 const float* __restrict__ dinv,
                                                 const void* __restrict__ bias,
                                                 float* __restrict__ Hf,
                                                 void* __restrict__ outp,
                                                 long long out_off,
                                                 const int* __restrict__ flags, int n) {
    const int gw = (int)((blockIdx.x * 256u + threadIdx.x) >> 6);
    const int lane = threadIdx.x & 63;
    if (gw >= n) return;
    constexpr int C = CPL * 64;
    const size_t base = (size_t)gw * C + lane * CPL;
    const bool f32 = flags[0] != 0;

    float acc[CPL];
    if constexpr (CPL == 2) {
        float2 v = *(const float2*)&G[base];
        acc[0] = v.x; acc[1] = v.y;
    } else {
        acc[0] = G[base];
    }

    const int e0 = off[gw];
    const int e1 = off[gw + 1];
    for (int e = e0; e < e1; ++e) {
        const int s = csr_src[e];
        const float* p = &G[(size_t)s * C + lane * CPL];
        if constexpr (CPL == 2) {
            float2 v = *(const float2*)p;
            acc[0] += v.x; acc[1] += v.y;
        } else {
            acc[0] += *p;
        }
    }

    const float d = dinv[gw];
    float o[CPL];
#pragma unroll
    for (int j = 0; j < CPL; ++j) {
        float bv = f32 ? ((const float*)bias)[lane * CPL + j]
                       : tof(((const __hip_bfloat16*)bias)[lane * CPL + j]);
        o[j] = d * acc[j] + bv;
        if (RELU) o[j] = fmaxf(o[j], 0.f);
    }
    if constexpr (WWS) {
        if constexpr (CPL == 2)
            *(float2*)&Hf[base] = make_float2(o[0], o[1]);
        else
            Hf[base] = o[0];
    }
    if constexpr (WOUT) {
        if (f32) {
            float* po = (float*)outp + out_off + base;
#pragma unroll
            for (int j = 0; j < CPL; ++j) po[j] = o[j];
        } else {
            __hip_bfloat16* po = (__hip_bfloat16*)outp + out_off + base;
#pragma unroll
            for (int j = 0; j < CPL; ++j) po[j] = __float2bfloat16(o[j]);
        }
    }
}

extern "C" void kernel_launch(void* const* d_in, const int* in_sizes, int n_in,
                              void* d_out, int out_size, void* d_ws, size_t ws_size,
                              hipStream_t stream) {
    const void* x  = d_in[0];
    const void* ei = d_in[1];
    const void* W1 = d_in[2];
    const void* b1 = d_in[3];
    const void* W2 = d_in[4];
    const void* b2 = d_in[5];
    const void* W3 = d_in[6];
    const void* b3 = d_in[7];

    const int N = in_sizes[0] / 128;  // 50000
    const int E = in_sizes[1] / 2;    // 800000

    char* p = (char*)d_ws;
    auto take = [&](size_t bytes) {
        char* q = p;
        p += (bytes + 255) & ~(size_t)255;
        return q;
    };
    int*   flags = (int*)take(64);
    int*   cnt  = (int*)take((size_t)N * 4);
    int*   off  = (int*)take((size_t)(N + 1) * 4);
    int*   cur  = (int*)take((size_t)N * 4);
    float* dinv = (float*)take((size_t)N * 4);
    int*   csr  = (int*)take((size_t)E * 4);
    float* bufA = (float*)take((size_t)N * 128 * 4);
    float* bufB = (float*)take((size_t)N * 128 * 4);
    (void)n_in; (void)out_size; (void)ws_size;

    detect_dtypes<<<1, 64, 0, stream>>>(x, ei, flags);
    hipMemsetAsync(cnt, 0, (size_t)N * 4, stream);
    const int eb = (E + 255) / 256;
    count_edges<<<eb, 256, 0, stream>>>(ei, cnt, flags, E);
    scan_kernel<<<1, 1024, 0, stream>>>(cnt, off, cur, dinv, N, E);
    fill_csr<<<eb, 256, 0, stream>>>(ei, cur, csr, flags, E);

    const int gb = (N + 15) / 16;
    const int ab = (N + 3) / 4;

    // Layer 1: g = dinv*(x@W1); h1 = relu(dinv*agg + b1) -> bufB (f32)
    gemm_scale<true, 128><<<gb, 256, 0, stream>>>(x, W1, dinv, bufA, flags, N);
    aggregate<2, true, true, false><<<ab, 256, 0, stream>>>(bufA, off, csr, dinv, b1, bufB, nullptr, 0, flags, N);
    // Layer 2: h2 -> bufB (f32, feeds layer 3) AND d_out[0 : N*128]
    gemm_scale<false, 128><<<gb, 256, 0, stream>>>(bufB, W2, dinv, bufA, flags, N);
    aggregate<2, true, true, true><<<ab, 256, 0, stream>>>(bufA, off, csr, dinv, b2, bufB, d_out, 0, flags, N);
    // Layer 3: 64 classes, no relu -> d_out[N*128 : N*192]
    gemm_scale<false, 64><<<gb, 256, 0, stream>>>(bufB, W3, dinv, bufA, flags, N);
    aggregate<1, false, false, true><<<ab, 256, 0, stream>>>(bufA, off, csr, dinv, b3, nullptr, d_out, (long long)N * 128, flags, N);
}

// Round 3
// 542.080 us; speedup vs baseline: 1.2793x; 1.2793x over previous
//
#include <hip/hip_runtime.h>
#include <hip/hip_bf16.h>

// GCN 3-layer forward on gfx950, dtype-robust.
// flags[0]=1 if floats are f32 (else bf16); flags[1]=1 if edges int64 (else int32).
// Pipeline: detect -> memset cnt -> count_edges -> deg_reduce -> scan_bsums
//           -> write_off -> fill_csr -> [gemm_scale -> aggregate] x3
// g = dinv*(X@W) in GEMM epilogue; aggregation = CSR gather-sum with self-loop
// as accumulator init; bias(+relu) in aggregate epilogue. Intermediates f32.

__device__ __forceinline__ float tof(float v) { return v; }
__device__ __forceinline__ float tof(__hip_bfloat16 v) { return __bfloat162float(v); }

// Two waves: wave0 classifies x dtype, wave1 classifies edge dtype.
__global__ void detect_dtypes(const void* __restrict__ x,
                              const void* __restrict__ ei,
                              int* __restrict__ flags) {
    const int t = threadIdx.x;
    const int lane = t & 63;
    if (t < 64) {
        // f32 data read as bf16: exponent field ~uniform -> most samples "bad".
        // bf16 N(0,1): exponents in ~[117,130] -> ~0 bad.
        const unsigned short* p = (const unsigned short*)x;
        int e = (p[2 * (lane * 16)] >> 7) & 0xFF;
        unsigned long long m = __ballot(e < 100 || e > 140);
        if (lane == 0) flags[0] = (__popcll(m) > 16) ? 1 : 0;
    } else if (t < 128) {
        // int64 values < 2^31: every odd int32 word is 0.
        const int* p = (const int*)ei;
        unsigned long long m = __ballot(p[2 * (lane * 16) + 1] != 0);
        if (lane == 0) flags[1] = (__popcll(m) < 2) ? 1 : 0;
    }
}

__device__ __forceinline__ int edge_at(const void* ei, long long idx, bool i64) {
    return i64 ? (int)((const long long*)ei)[idx] : ((const int*)ei)[idx];
}

__global__ void count_edges(const void* __restrict__ ei, int* __restrict__ cnt,
                            const int* __restrict__ flags, int e) {
    int i = blockIdx.x * 256 + threadIdx.x;
    if (i < e) {
        const bool i64 = flags[1] != 0;
        atomicAdd(&cnt[edge_at(ei, (long long)e + i, i64)], 1);
    }
}

// Stage 1: per-block (256-wide, coalesced) sum of cnt -> bsum[block]
__global__ __launch_bounds__(256) void deg_reduce(const int* __restrict__ cnt,
                                                  int* __restrict__ bsum, int n) {
    __shared__ int sm[4];
    const int t = threadIdx.x;
    int i = blockIdx.x * 256 + t;
    int v = (i < n) ? cnt[i] : 0;
#pragma unroll
    for (int d = 32; d >= 1; d >>= 1) v += __shfl_down(v, d);
    if ((t & 63) == 0) sm[t >> 6] = v;
    __syncthreads();
    if (t == 0) bsum[blockIdx.x] = sm[0] + sm[1] + sm[2] + sm[3];
}

// Stage 2: one block scans the (<=256) block sums -> exclusive bases.
__global__ __launch_bounds__(256) void scan_bsums(int* __restrict__ bsum, int nb) {
    __shared__ int sm[256];
    const int t = threadIdx.x;
    sm[t] = (t < nb) ? bsum[t] : 0;
    __syncthreads();
#pragma unroll
    for (int d = 1; d < 256; d <<= 1) {
        int v = (t >= d) ? sm[t - d] : 0;
        __syncthreads();
        sm[t] += v;
        __syncthreads();
    }
    if (t < nb) bsum[t] = (t == 0) ? 0 : sm[t - 1];  // exclusive base
}

// Stage 3: per-block exclusive scan of cnt + base -> off/cur; dinv = rsqrt(deg+1).
__global__ __launch_bounds__(256) void write_off(const int* __restrict__ cnt,
                                                 const int* __restrict__ bsum,
                                                 int* __restrict__ off,
                                                 int* __restrict__ cur,
                                                 float* __restrict__ dinv,
                                                 int n, int e_total) {
    __shared__ int sm[256];
    const int t = threadIdx.x;
    const int i = blockIdx.x * 256 + t;
    const int c = (i < n) ? cnt[i] : 0;
    sm[t] = c;
    __syncthreads();
#pragma unroll
    for (int d = 1; d < 256; d <<= 1) {
        int v = (t >= d) ? sm[t - d] : 0;
        __syncthreads();
        sm[t] += v;
        __syncthreads();
    }
    if (i < n) {
        int o = bsum[blockIdx.x] + sm[t] - c;  // exclusive
        off[i] = o;
        cur[i] = o;
        dinv[i] = rsqrtf((float)(c + 1));
        if (i == n - 1) off[n] = e_total;
    }
}

__global__ void fill_csr(const void* __restrict__ ei, int* __restrict__ cur,
                         int* __restrict__ csr_src, const int* __restrict__ flags, int e) {
    int i = blockIdx.x * 256 + threadIdx.x;
    if (i < e) {
        const bool i64 = flags[1] != 0;
        int r = edge_at(ei, i, i64);
        int c = edge_at(ei, (long long)e + i, i64);
        int p = atomicAdd(&cur[c], 1);
        csr_src[p] = r;
    }
}

// G[i][c] = dinv[i] * sum_k X[i][k]*W[k][c]. 256 threads, 16 rows x COUT/blk.
template <bool XFLAG, int COUT>
__global__ __launch_bounds__(256) void gemm_scale(const void* __restrict__ Xv,
                                                  const void* __restrict__ Wv,
                                                  const float* __restrict__ dinv,
                                                  float* __restrict__ G,
                                                  const int* __restrict__ flags, int n) {
    constexpr int ROWS = 16;
    constexpr int KC = 64;
    __shared__ float wlds[KC * COUT];
    __shared__ float xlds[ROWS * 128];
    const int t = threadIdx.x;
    const int row0 = blockIdx.x * ROWS;
    const bool f32 = flags[0] != 0;
    const bool xf32 = XFLAG ? f32 : true;

    if (xf32) {
        const float* X = (const float*)Xv;
        for (int i = t; i < ROWS * 128; i += 256) {
            int r = i >> 7;
            xlds[i] = (row0 + r < n) ? X[(size_t)(row0 + r) * 128 + (i & 127)] : 0.f;
        }
    } else {
        const __hip_bfloat16* X = (const __hip_bfloat16*)Xv;
        for (int i = t; i < ROWS * 128; i += 256) {
            int r = i >> 7;
            xlds[i] = (row0 + r < n) ? tof(X[(size_t)(row0 + r) * 128 + (i & 127)]) : 0.f;
        }
    }

    float acc[8];
#pragma unroll
    for (int j = 0; j < 8; ++j) acc[j] = 0.f;

    const int c4 = (COUT == 128) ? ((t & 31) * 4) : ((t & 15) * 4);
    const int r0 = (COUT == 128) ? ((t >> 5) * 2) : (t >> 4);

    for (int kc = 0; kc < 128; kc += KC) {
        __syncthreads();
        if (f32) {
            const float* W = (const float*)Wv;
            for (int i = t; i < KC * COUT; i += 256)
                wlds[i] = W[(size_t)kc * COUT + i];
        } else {
            const __hip_bfloat16* W = (const __hip_bfloat16*)Wv;
            for (int i = t; i < KC * COUT; i += 256)
                wlds[i] = tof(W[(size_t)kc * COUT + i]);
        }
        __syncthreads();
#pragma unroll
        for (int k = 0; k < KC; ++k) {
            const float4 w = *(const float4*)&wlds[k * COUT + c4];
            if (COUT == 128) {
                float x0 = xlds[r0 * 128 + kc + k];
                float x1 = xlds[(r0 + 1) * 128 + kc + k];
                acc[0] += x0 * w.x; acc[1] += x0 * w.y;
                acc[2] += x0 * w.z; acc[3] += x0 * w.w;
                acc[4] += x1 * w.x; acc[5] += x1 * w.y;
                acc[6] += x1 * w.z; acc[7] += x1 * w.w;
            } else {
                float x0 = xlds[r0 * 128 + kc + k];
                acc[0] += x0 * w.x; acc[1] += x0 * w.y;
                acc[2] += x0 * w.z; acc[3] += x0 * w.w;
            }
        }
    }

    const int nr = (COUT == 128) ? 2 : 1;
#pragma unroll
    for (int rr = 0; rr < nr; ++rr) {
        int row = row0 + r0 + rr;
        if (row < n) {
            float d = dinv[row];
            float4 o;
            o.x = d * acc[rr * 4 + 0];
            o.y = d * acc[rr * 4 + 1];
            o.z = d * acc[rr * 4 + 2];
            o.w = d * acc[rr * 4 + 3];
            *(float4*)&G[(size_t)row * COUT + c4] = o;
        }
    }
}

// One wave per destination node; lane handles CPL channels (CPL*64 == C).
template <int CPL, bool RELU, bool WWS, bool WOUT>
__global__ __launch_bounds__(256) void aggregate(const float* __restrict__ G,
                                                 const int* __restrict__ off,
                                                 const int* __restrict__ csr_src,
                                                 const float* __restrict__ dinv,
                                                 const void* __restrict__ bias,
                                                 float* __restrict__ Hf,
                                                 void* __restrict__ outp,
                                                 long long out_off,
                                                 const int* __restrict__ flags, int n) {
    const int gw = (int)((blockIdx.x * 256u + threadIdx.x) >> 6);
    const int lane = threadIdx.x & 63;
    if (gw >= n) return;
    constexpr int C = CPL * 64;
    const size_t base = (size_t)gw * C + lane * CPL;
    const bool f32 = flags[0] != 0;

    float acc[CPL];
    if constexpr (CPL == 2) {
        float2 v = *(const float2*)&G[base];
        acc[0] = v.x; acc[1] = v.y;
    } else {
        acc[0] = G[base];
    }

    const int e0 = off[gw];
    const int e1 = off[gw + 1];
    for (int e = e0; e < e1; ++e) {
        const int s = csr_src[e];
        const float* p = &G[(size_t)s * C + lane * CPL];
        if constexpr (CPL == 2) {
            float2 v = *(const float2*)p;
            acc[0] += v.x; acc[1] += v.y;
        } else {
            acc[0] += *p;
        }
    }

    const float d = dinv[gw];
    float o[CPL];
#pragma unroll
    for (int j = 0; j < CPL; ++j) {
        float bv = f32 ? ((const float*)bias)[lane * CPL + j]
                       : tof(((const __hip_bfloat16*)bias)[lane * CPL + j]);
        o[j] = d * acc[j] + bv;
        if (RELU) o[j] = fmaxf(o[j], 0.f);
    }
    if constexpr (WWS) {
        if constexpr (CPL == 2)
            *(float2*)&Hf[base] = make_float2(o[0], o[1]);
        else
            Hf[base] = o[0];
    }
    if constexpr (WOUT) {
        if (f32) {
            float* po = (float*)outp + out_off + base;
#pragma unroll
            for (int j = 0; j < CPL; ++j) po[j] = o[j];
        } else {
            __hip_bfloat16* po = (__hip_bfloat16*)outp + out_off + base;
#pragma unroll
            for (int j = 0; j < CPL; ++j) po[j] = __float2bfloat16(o[j]);
        }
    }
}

extern "C" void kernel_launch(void* const* d_in, const int* in_sizes, int n_in,
                              void* d_out, int out_size, void* d_ws, size_t ws_size,
                              hipStream_t stream) {
    const void* x  = d_in[0];
    const void* ei = d_in[1];
    const void* W1 = d_in[2];
    const void* b1 = d_in[3];
    const void* W2 = d_in[4];
    const void* b2 = d_in[5];
    const void* W3 = d_in[6];
    const void* b3 = d_in[7];

    const int N = in_sizes[0] / 128;  // 50000
    const int E = in_sizes[1] / 2;    // 800000

    char* p = (char*)d_ws;
    auto take = [&](size_t bytes) {
        char* q = p;
        p += (bytes + 255) & ~(size_t)255;
        return q;
    };
    int*   flags = (int*)take(64);
    int*   cnt  = (int*)take((size_t)N * 4);
    int*   bsum = (int*)take(1024);
    int*   off  = (int*)take((size_t)(N + 1) * 4);
    int*   cur  = (int*)take((size_t)N * 4);
    float* dinv = (float*)take((size_t)N * 4);
    int*   csr  = (int*)take((size_t)E * 4);
    float* bufA = (float*)take((size_t)N * 128 * 4);
    float* bufB = (float*)take((size_t)N * 128 * 4);
    (void)n_in; (void)out_size; (void)ws_size;

    const int nb = (N + 255) / 256;  // 196 (must be <= 256)
    const int eb = (E + 255) / 256;

    detect_dtypes<<<1, 128, 0, stream>>>(x, ei, flags);
    hipMemsetAsync(cnt, 0, (size_t)N * 4, stream);
    count_edges<<<eb, 256, 0, stream>>>(ei, cnt, flags, E);
    deg_reduce<<<nb, 256, 0, stream>>>(cnt, bsum, N);
    scan_bsums<<<1, 256, 0, stream>>>(bsum, nb);
    write_off<<<nb, 256, 0, stream>>>(cnt, bsum, off, cur, dinv, N, E);
    fill_csr<<<eb, 256, 0, stream>>>(ei, cur, csr, flags, E);

    const int gb = (N + 15) / 16;
    const int ab = (N + 3) / 4;

    // Layer 1: g = dinv*(x@W1); h1 = relu(dinv*agg + b1) -> bufB (f32)
    gemm_scale<true, 128><<<gb, 256, 0, stream>>>(x, W1, dinv, bufA, flags, N);
    aggregate<2, true, true, false><<<ab, 256, 0, stream>>>(bufA, off, csr, dinv, b1, bufB, nullptr, 0, flags, N);
    // Layer 2: h2 -> bufB (f32, feeds layer 3) AND d_out[0 : N*128]
    gemm_scale<false, 128><<<gb, 256, 0, stream>>>(bufB, W2, dinv, bufA, flags, N);
    aggregate<2, true, true, true><<<ab, 256, 0, stream>>>(bufA, off, csr, dinv, b2, bufB, d_out, 0, flags, N);
    // Layer 3: 64 classes, no relu -> d_out[N*128 : N*192]
    gemm_scale<false, 64><<<gb, 256, 0, stream>>>(bufB, W3, dinv, bufA, flags, N);
    aggregate<1, false, false, true><<<ab, 256, 0, stream>>>(bufA, off, csr, dinv, b3, nullptr, d_out, (long long)N * 128, flags, N);
}

// Round 4
// 446.210 us; speedup vs baseline: 1.5541x; 1.2149x over previous
//
#include <hip/hip_runtime.h>
#include <hip/hip_bf16.h>

// GCN 3-layer forward on gfx950, dtype-robust.
// flags[0]=1 if floats are f32 (else bf16); flags[1]=1 if edges int64 (else int32).
// Pipeline: detect -> memset cnt -> count_edges -> deg_reduce -> scan_bsums
//           -> write_off -> fill_csr -> [gemm_scale -> aggregate] x3
// Aggregate is latency-optimized: 64-edge index chunks loaded cooperatively
// (one coalesced load instead of per-edge scalar loads), 8-wide unrolled
// gather with fma masking so 8 row-loads are in flight per wave.

__device__ __forceinline__ float tof(float v) { return v; }
__device__ __forceinline__ float tof(__hip_bfloat16 v) { return __bfloat162float(v); }

__global__ void detect_dtypes(const void* __restrict__ x,
                              const void* __restrict__ ei,
                              int* __restrict__ flags) {
    const int t = threadIdx.x;
    const int lane = t & 63;
    if (t < 64) {
        const unsigned short* p = (const unsigned short*)x;
        int e = (p[2 * (lane * 16)] >> 7) & 0xFF;
        unsigned long long m = __ballot(e < 100 || e > 140);
        if (lane == 0) flags[0] = (__popcll(m) > 16) ? 1 : 0;
    } else if (t < 128) {
        const int* p = (const int*)ei;
        unsigned long long m = __ballot(p[2 * (lane * 16) + 1] != 0);
        if (lane == 0) flags[1] = (__popcll(m) < 2) ? 1 : 0;
    }
}

__device__ __forceinline__ int edge_at(const void* ei, long long idx, bool i64) {
    return i64 ? (int)((const long long*)ei)[idx] : ((const int*)ei)[idx];
}

__global__ void count_edges(const void* __restrict__ ei, int* __restrict__ cnt,
                            const int* __restrict__ flags, int e) {
    int i = blockIdx.x * 256 + threadIdx.x;
    if (i < e) {
        const bool i64 = flags[1] != 0;
        atomicAdd(&cnt[edge_at(ei, (long long)e + i, i64)], 1);
    }
}

__global__ __launch_bounds__(256) void deg_reduce(const int* __restrict__ cnt,
                                                  int* __restrict__ bsum, int n) {
    __shared__ int sm[4];
    const int t = threadIdx.x;
    int i = blockIdx.x * 256 + t;
    int v = (i < n) ? cnt[i] : 0;
#pragma unroll
    for (int d = 32; d >= 1; d >>= 1) v += __shfl_down(v, d);
    if ((t & 63) == 0) sm[t >> 6] = v;
    __syncthreads();
    if (t == 0) bsum[blockIdx.x] = sm[0] + sm[1] + sm[2] + sm[3];
}

__global__ __launch_bounds__(256) void scan_bsums(int* __restrict__ bsum, int nb) {
    __shared__ int sm[256];
    const int t = threadIdx.x;
    sm[t] = (t < nb) ? bsum[t] : 0;
    __syncthreads();
#pragma unroll
    for (int d = 1; d < 256; d <<= 1) {
        int v = (t >= d) ? sm[t - d] : 0;
        __syncthreads();
        sm[t] += v;
        __syncthreads();
    }
    if (t < nb) bsum[t] = (t == 0) ? 0 : sm[t - 1];
}

__global__ __launch_bounds__(256) void write_off(const int* __restrict__ cnt,
                                                 const int* __restrict__ bsum,
                                                 int* __restrict__ off,
                                                 int* __restrict__ cur,
                                                 float* __restrict__ dinv,
                                                 int n, int e_total) {
    __shared__ int sm[256];
    const int t = threadIdx.x;
    const int i = blockIdx.x * 256 + t;
    const int c = (i < n) ? cnt[i] : 0;
    sm[t] = c;
    __syncthreads();
#pragma unroll
    for (int d = 1; d < 256; d <<= 1) {
        int v = (t >= d) ? sm[t - d] : 0;
        __syncthreads();
        sm[t] += v;
        __syncthreads();
    }
    if (i < n) {
        int o = bsum[blockIdx.x] + sm[t] - c;
        off[i] = o;
        cur[i] = o;
        dinv[i] = rsqrtf((float)(c + 1));
        if (i == n - 1) off[n] = e_total;
    }
}

__global__ void fill_csr(const void* __restrict__ ei, int* __restrict__ cur,
                         int* __restrict__ csr_src, const int* __restrict__ flags, int e) {
    int i = blockIdx.x * 256 + threadIdx.x;
    if (i < e) {
        const bool i64 = flags[1] != 0;
        int r = edge_at(ei, i, i64);
        int c = edge_at(ei, (long long)e + i, i64);
        int p = atomicAdd(&cur[c], 1);
        csr_src[p] = r;
    }
}

// G[i][c] = dinv[i] * sum_k X[i][k]*W[k][c]. 256 threads, 16 rows x COUT/blk.
template <bool XFLAG, int COUT>
__global__ __launch_bounds__(256) void gemm_scale(const void* __restrict__ Xv,
                                                  const void* __restrict__ Wv,
                                                  const float* __restrict__ dinv,
                                                  float* __restrict__ G,
                                                  const int* __restrict__ flags, int n) {
    constexpr int ROWS = 16;
    constexpr int KC = 64;
    __shared__ float wlds[KC * COUT];
    __shared__ float xlds[ROWS * 128];
    const int t = threadIdx.x;
    const int row0 = blockIdx.x * ROWS;
    const bool f32 = flags[0] != 0;
    const bool xf32 = XFLAG ? f32 : true;

    if (xf32) {
        const float* X = (const float*)Xv;
        for (int i = t; i < ROWS * 128; i += 256) {
            int r = i >> 7;
            xlds[i] = (row0 + r < n) ? X[(size_t)(row0 + r) * 128 + (i & 127)] : 0.f;
        }
    } else {
        const __hip_bfloat16* X = (const __hip_bfloat16*)Xv;
        for (int i = t; i < ROWS * 128; i += 256) {
            int r = i >> 7;
            xlds[i] = (row0 + r < n) ? tof(X[(size_t)(row0 + r) * 128 + (i & 127)]) : 0.f;
        }
    }

    float acc[8];
#pragma unroll
    for (int j = 0; j < 8; ++j) acc[j] = 0.f;

    const int c4 = (COUT == 128) ? ((t & 31) * 4) : ((t & 15) * 4);
    const int r0 = (COUT == 128) ? ((t >> 5) * 2) : (t >> 4);

    for (int kc = 0; kc < 128; kc += KC) {
        __syncthreads();
        if (f32) {
            const float* W = (const float*)Wv;
            for (int i = t; i < KC * COUT; i += 256)
                wlds[i] = W[(size_t)kc * COUT + i];
        } else {
            const __hip_bfloat16* W = (const __hip_bfloat16*)Wv;
            for (int i = t; i < KC * COUT; i += 256)
                wlds[i] = tof(W[(size_t)kc * COUT + i]);
        }
        __syncthreads();
#pragma unroll
        for (int k = 0; k < KC; ++k) {
            const float4 w = *(const float4*)&wlds[k * COUT + c4];
            if (COUT == 128) {
                float x0 = xlds[r0 * 128 + kc + k];
                float x1 = xlds[(r0 + 1) * 128 + kc + k];
                acc[0] += x0 * w.x; acc[1] += x0 * w.y;
                acc[2] += x0 * w.z; acc[3] += x0 * w.w;
                acc[4] += x1 * w.x; acc[5] += x1 * w.y;
                acc[6] += x1 * w.z; acc[7] += x1 * w.w;
            } else {
                float x0 = xlds[r0 * 128 + kc + k];
                acc[0] += x0 * w.x; acc[1] += x0 * w.y;
                acc[2] += x0 * w.z; acc[3] += x0 * w.w;
            }
        }
    }

    const int nr = (COUT == 128) ? 2 : 1;
#pragma unroll
    for (int rr = 0; rr < nr; ++rr) {
        int row = row0 + r0 + rr;
        if (row < n) {
            float d = dinv[row];
            float4 o;
            o.x = d * acc[rr * 4 + 0];
            o.y = d * acc[rr * 4 + 1];
            o.z = d * acc[rr * 4 + 2];
            o.w = d * acc[rr * 4 + 3];
            *(float4*)&G[(size_t)row * COUT + c4] = o;
        }
    }
}

// One wave per destination node; lane handles CPL channels (CPL*64 == C).
// Index chunks (64 edges) fetched cooperatively; 8-wide unrolled gather with
// fma masking keeps 8 row-loads in flight per wave.
template <int CPL, bool RELU, bool WWS, bool WOUT>
__global__ __launch_bounds__(256) void aggregate(const float* __restrict__ G,
                                                 const int* __restrict__ off,
                                                 const int* __restrict__ csr_src,
                                                 const float* __restrict__ dinv,
                                                 const void* __restrict__ bias,
                                                 float* __restrict__ Hf,
                                                 void* __restrict__ outp,
                                                 long long out_off,
                                                 const int* __restrict__ flags, int n) {
    const int gw = (int)((blockIdx.x * 256u + threadIdx.x) >> 6);
    const int lane = threadIdx.x & 63;
    if (gw >= n) return;
    constexpr int C = CPL * 64;
    const size_t base = (size_t)gw * C + lane * CPL;
    const bool f32 = flags[0] != 0;

    float a0, a1;
    if constexpr (CPL == 2) {
        float2 v = *(const float2*)&G[base];
        a0 = v.x; a1 = v.y;
    } else {
        a0 = G[base]; a1 = 0.f;
    }

    const int e0 = off[gw];
    const int e1 = off[gw + 1];
    const int col = lane * CPL;

    for (int bs = e0; bs < e1; bs += 64) {
        const int cnt = min(64, e1 - bs);
        // cooperative index fetch: one coalesced load for up to 64 edges
        const int myidx = (bs + lane < e1) ? csr_src[bs + lane] : 0;
        for (int j = 0; j < cnt; j += 8) {
#pragma unroll
            for (int k = 0; k < 8; ++k) {
                const int jj = min(j + k, cnt - 1);       // uniform
                const int s = __shfl(myidx, jj);
                const float m = (j + k < cnt) ? 1.f : 0.f;
                if constexpr (CPL == 2) {
                    float2 v = *(const float2*)&G[(size_t)s * C + col];
                    a0 = fmaf(m, v.x, a0);
                    a1 = fmaf(m, v.y, a1);
                } else {
                    float v = G[(size_t)s * C + col];
                    a0 = fmaf(m, v, a0);
                }
            }
        }
    }

    const float d = dinv[gw];
    float o[CPL];
    float accs[2] = {a0, a1};
#pragma unroll
    for (int j = 0; j < CPL; ++j) {
        float bv = f32 ? ((const float*)bias)[col + j]
                       : tof(((const __hip_bfloat16*)bias)[col + j]);
        o[j] = d * accs[j] + bv;
        if (RELU) o[j] = fmaxf(o[j], 0.f);
    }
    if constexpr (WWS) {
        if constexpr (CPL == 2)
            *(float2*)&Hf[base] = make_float2(o[0], o[1]);
        else
            Hf[base] = o[0];
    }
    if constexpr (WOUT) {
        if (f32) {
            float* po = (float*)outp + out_off + base;
#pragma unroll
            for (int j = 0; j < CPL; ++j) po[j] = o[j];
        } else {
            __hip_bfloat16* po = (__hip_bfloat16*)outp + out_off + base;
#pragma unroll
            for (int j = 0; j < CPL; ++j) po[j] = __float2bfloat16(o[j]);
        }
    }
}

extern "C" void kernel_launch(void* const* d_in, const int* in_sizes, int n_in,
                              void* d_out, int out_size, void* d_ws, size_t ws_size,
                              hipStream_t stream) {
    const void* x  = d_in[0];
    const void* ei = d_in[1];
    const void* W1 = d_in[2];
    const void* b1 = d_in[3];
    const void* W2 = d_in[4];
    const void* b2 = d_in[5];
    const void* W3 = d_in[6];
    const void* b3 = d_in[7];

    const int N = in_sizes[0] / 128;  // 50000
    const int E = in_sizes[1] / 2;    // 800000

    char* p = (char*)d_ws;
    auto take = [&](size_t bytes) {
        char* q = p;
        p += (bytes + 255) & ~(size_t)255;
        return q;
    };
    int*   flags = (int*)take(64);
    int*   cnt  = (int*)take((size_t)N * 4);
    int*   bsum = (int*)take(1024);
    int*   off  = (int*)take((size_t)(N + 1) * 4);
    int*   cur  = (int*)take((size_t)N * 4);
    float* dinv = (float*)take((size_t)N * 4);
    int*   csr  = (int*)take((size_t)E * 4);
    float* bufA = (float*)take((size_t)N * 128 * 4);
    float* bufB = (float*)take((size_t)N * 128 * 4);
    (void)n_in; (void)out_size; (void)ws_size;

    const int nb = (N + 255) / 256;  // 196 (<= 256)
    const int eb = (E + 255) / 256;

    detect_dtypes<<<1, 128, 0, stream>>>(x, ei, flags);
    hipMemsetAsync(cnt, 0, (size_t)N * 4, stream);
    count_edges<<<eb, 256, 0, stream>>>(ei, cnt, flags, E);
    deg_reduce<<<nb, 256, 0, stream>>>(cnt, bsum, N);
    scan_bsums<<<1, 256, 0, stream>>>(bsum, nb);
    write_off<<<nb, 256, 0, stream>>>(cnt, bsum, off, cur, dinv, N, E);
    fill_csr<<<eb, 256, 0, stream>>>(ei, cur, csr, flags, E);

    const int gb = (N + 15) / 16;
    const int ab = (N + 3) / 4;

    // Layer 1: g = dinv*(x@W1); h1 = relu(dinv*agg + b1) -> bufB (f32)
    gemm_scale<true, 128><<<gb, 256, 0, stream>>>(x, W1, dinv, bufA, flags, N);
    aggregate<2, true, true, false><<<ab, 256, 0, stream>>>(bufA, off, csr, dinv, b1, bufB, nullptr, 0, flags, N);
    // Layer 2: h2 -> bufB (f32, feeds layer 3) AND d_out[0 : N*128]
    gemm_scale<false, 128><<<gb, 256, 0, stream>>>(bufB, W2, dinv, bufA, flags, N);
    aggregate<2, true, true, true><<<ab, 256, 0, stream>>>(bufA, off, csr, dinv, b2, bufB, d_out, 0, flags, N);
    // Layer 3: 64 classes, no relu -> d_out[N*128 : N*192]
    gemm_scale<false, 64><<<gb, 256, 0, stream>>>(bufB, W3, dinv, bufA, flags, N);
    aggregate<1, false, false, true><<<ab, 256, 0, stream>>>(bufA, off, csr, dinv, b3, nullptr, d_out, (long long)N * 128, flags, N);
}